// Round 16
// baseline (70.883 us; speedup 1.0000x reference)
//
#include <hip/hip_runtime.h>
#include <hip/hip_bf16.h>

#define LOG2E 1.4426950408889634f
#define LN2   0.6931471805599453f

#define BATCH 32
#define SEQ   512
#define DIM   128
#define NMAT  128                   // 4 pairs * 32 batches

#define EXP2F(x) __builtin_amdgcn_exp2f(x)
#define LOG2F(x) __builtin_amdgcn_logf(x)

typedef short bf16x8 __attribute__((ext_vector_type(8)));
typedef float f32x4 __attribute__((ext_vector_type(4)));
typedef __attribute__((address_space(1))) const void gas_void;
typedef __attribute__((address_space(3))) void las_void;

// lane i <- lane i-1 (wave_shr:1); lane 0 receives 0 (== +inf cost in W-domain)
__device__ __forceinline__ float dpp_shr1(float x) {
  return __int_as_float(__builtin_amdgcn_update_dpp(
      0, __float_as_int(x), 0x138, 0xF, 0xF, false));
}
// lane i <- lane i+1 (wave_shl:1); lane 63 receives 0
__device__ __forceinline__ float dpp_shl1(float x) {
  return __int_as_float(__builtin_amdgcn_update_dpp(
      0, __float_as_int(x), 0x130, 0xF, 0xF, false));
}
// x = max(x, dpp<CTRL>(x)); lanes w/o source keep x
template <int CTRL>
__device__ __forceinline__ float dpp_max(float x) {
  int y = __builtin_amdgcn_update_dpp(
      __float_as_int(x), __float_as_int(x), CTRL, 0xF, 0xF, false);
  return fmaxf(x, __int_as_float(y));
}

// ---------------------------------------------------------------------------
// Kernel 1 (prep): normalize rows, split to bf16 hi/lo, interleave.
// ---------------------------------------------------------------------------
__device__ __forceinline__ unsigned short f2bf_rn(float f) {
  unsigned u = __float_as_uint(f);
  u = (u + 0x7FFF + ((u >> 16) & 1)) >> 16;
  return (unsigned short)u;
}
__device__ __forceinline__ float bf2f(unsigned short h) {
  return __uint_as_float(((unsigned)h) << 16);
}

__global__ __launch_bounds__(256) void prep_kernel(
    const float* __restrict__ tgt, const float* __restrict__ oth,
    const float* __restrict__ x, unsigned short* __restrict__ Y) {
  int gid  = blockIdx.x * blockDim.x + threadIdx.x;
  int wave = gid >> 6;
  int lane = threadIdx.x & 63;
  int set = wave / (BATCH * SEQ);
  int row = wave % (BATCH * SEQ);
  const float* src = (set == 0) ? tgt : ((set == 1) ? oth : x);
  const float2* p = (const float2*)(src + (size_t)row * DIM);
  float2 v = p[lane];
  float s = v.x * v.x + v.y * v.y;
#pragma unroll
  for (int off = 32; off; off >>= 1) s += __shfl_xor(s, off);
  float inv = 1.0f / (sqrtf(s) + 1e-8f);
  float y0 = v.x * inv, y1 = v.y * inv;
  unsigned short h0 = f2bf_rn(y0);
  unsigned short l0 = f2bf_rn(y0 - bf2f(h0));
  unsigned short h1 = f2bf_rn(y1);
  unsigned short l1 = f2bf_rn(y1 - bf2f(h1));
  ushort4 st = {h0, l0, h1, l1};
  ((ushort4*)(Y + (size_t)wave * 256))[lane] = st;
}

// ---------------------------------------------------------------------------
// Kernel 2 (costmm): band-stripe bf16 MFMA GEMM -> Sband[i][d+64] = 2^(-D'),
// j-invalid -> 0. GRID NOW (NMAT, 8): all 8 stripes of a matrix share
// id mod 8 -> same XCD -> Y rows L2-local (per-XCD working set ~3MB).
// ---------------------------------------------------------------------------
__global__ __launch_bounds__(256) void costmm_kernel(
    const unsigned short* __restrict__ Y, float* __restrict__ Sband) {
  __shared__ unsigned short As[64 * 64];       // 8 KB
  __shared__ unsigned short Bs[192 * 64];      // 24 KB

  const int m = blockIdx.x;                    // matrix (x -> same-XCD stripes)
  const int s = blockIdx.y;                    // stripe 0..7
  const int p = m >> 5, b = m & 31;
  const int setA = (p == 1 || p == 3) ? 0 : 1;
  const int setB = (p <= 1) ? 2 : setA;
  const unsigned short* YA = Y + ((size_t)(setA * BATCH + b)) * SEQ * 256;
  const unsigned short* YB = Y + ((size_t)(setB * BATCH + b)) * SEQ * 256;
  const int i0 = s * 64;
  const int j0 = s * 64 - 64;

  const int t = threadIdx.x;
  const int w = t >> 6, l = t & 63;

  f32x4 acc[4][3];
#pragma unroll
  for (int a = 0; a < 4; ++a)
#pragma unroll
    for (int c = 0; c < 3; ++c) acc[a][c] = (f32x4){0.f, 0.f, 0.f, 0.f};

  const int srow_off = l >> 3;
  const int scb      = ((l & 7) * 16) ^ ((srow_off & 7) * 16);

  for (int slab = 0; slab < 4; ++slab) {
    if (slab) __syncthreads();
#pragma unroll
    for (int q2 = 0; q2 < 2; ++q2) {
      int wi = w * 2 + q2;
      int r = wi * 8 + srow_off;
      const unsigned short* gA = YA + (size_t)(i0 + r) * 256 + slab * 64 + (scb >> 1);
      __builtin_amdgcn_global_load_lds((gas_void*)gA, (las_void*)(As + wi * 512), 16, 0, 0);
    }
#pragma unroll
    for (int q6 = 0; q6 < 6; ++q6) {
      int wi = w * 6 + q6;
      int r = wi * 8 + srow_off;               // 0..191
      int j = j0 + r; j = (j < 0) ? 0 : ((j > 511) ? 511 : j);
      const unsigned short* gB = YB + (size_t)j * 256 + slab * 64 + (scb >> 1);
      __builtin_amdgcn_global_load_lds((gas_void*)gB, (las_void*)(Bs + wi * 512), 16, 0, 0);
    }
    asm volatile("s_waitcnt vmcnt(0)" ::: "memory");
    __syncthreads();

#pragma unroll
    for (int ks = 0; ks < 2; ++ks) {
      bf16x8 af[4], bfr[3];
#pragma unroll
      for (int f = 0; f < 4; ++f) {
        int ra = f * 16 + (l & 15);
        int ca = (ks * 64 + (l >> 4) * 16) ^ ((ra & 7) << 4);
        af[f] = *(const bf16x8*)((const char*)As + ra * 128 + ca);
      }
#pragma unroll
      for (int f = 0; f < 3; ++f) {
        int rb = w * 48 + f * 16 + (l & 15);
        int cb = (ks * 64 + (l >> 4) * 16) ^ ((rb & 7) << 4);
        bfr[f] = *(const bf16x8*)((const char*)Bs + rb * 128 + cb);
      }
#pragma unroll
      for (int fm = 0; fm < 4; ++fm)
#pragma unroll
        for (int fn = 0; fn < 3; ++fn)
          acc[fm][fn] = __builtin_amdgcn_mfma_f32_16x16x32_bf16(
              af[fm], bfr[fn], acc[fm][fn], 0, 0, 0);
    }
  }

  float* Sbm = Sband + (size_t)m * (SEQ * 128);
#pragma unroll
  for (int fm = 0; fm < 4; ++fm)
#pragma unroll
    for (int fn = 0; fn < 3; ++fn)
#pragma unroll
      for (int q = 0; q < 4; ++q) {
        int r = fm * 16 + (l >> 4) * 4 + q;    // 0..63  (i = i0+r)
        int c = w * 48 + fn * 16 + (l & 15);   // 0..191 (j = j0+c)
        unsigned crm = (unsigned)(c - r);      // d+64
        if (crm < 128u) {
          int jreal = j0 + c;
          float dp = (1.0f - acc[fm][fn][q]) * LOG2E;
          float sval = ((unsigned)jreal < 512u) ? EXP2F(-dp) : 0.0f;
          Sbm[((size_t)(i0 + r) << 7) + crm] = sval;
        }
      }
}

// ---------------------------------------------------------------------------
// Kernel 3 (dtw): banded soft-DTW, linear domain, one wave/matrix, zero
// barriers. Mask-free gather: staging redirects rows>=512 to a zero page
// (per-lane addr select), ring slots 64..127 zero-filled once (covers
// negative rows in chunks 0-1). Rescale every 2 chunks (64 steps: max-lane
// W >= ~2^-92, safe).
// ---------------------------------------------------------------------------
__global__ __launch_bounds__(64) void dtw_kernel(
    const float* __restrict__ Sband, const float* __restrict__ zerorow,
    float* __restrict__ raw) {
  __shared__ float stg[128][128];              // 64 KB ring (slot = row & 127)
  const int t = threadIdx.x;
  const int m = blockIdx.x;
  const float* Db = Sband + (size_t)m * (SEQ * 128);

  float v0 = (t == 32) ? 1.0f : 0.0f;          // W[0][0] = 2^0 at d=0
  float v1 = 0.0f;
  int otally = 0;

  // zero-fill slots 64..127 (read as rows <0 / >=512 in early chunks)
  {
    float4 z4 = make_float4(0.f, 0.f, 0.f, 0.f);
#pragma unroll
    for (int q = 0; q < 32; ++q) {
      int row = 64 + q * 2 + (t >> 5);
      *(float4*)&stg[row][(t & 31) * 4] = z4;
    }
  }
  // prologue: stage rows 0..63 (32 instrs, 2 rows/instr)
#pragma unroll
  for (int q = 0; q < 32; ++q) {
    int row = q * 2;
    __builtin_amdgcn_global_load_lds(
        (gas_void*)(Db + (size_t)row * 128 + t * 4),
        (las_void*)(&stg[row][0]), 16, 0, 0);
  }

#define CHUNK(C_)                                                             \
  {                                                                           \
    const int c = (C_);                                                       \
    {                                                                         \
      int rbase = 16 * c + 64;                                                \
      _Pragma("unroll")                                                       \
      for (int q = 0; q < 8; ++q) {                                           \
        int row = rbase + q * 2;                                              \
        int srow = row + (t >> 5);                                            \
        const float* src = (srow < 512) ? (Db + (size_t)srow * 128 + (t & 31) * 4) \
                                        : (zerorow + (t & 31) * 4);           \
        __builtin_amdgcn_global_load_lds((gas_void*)src,                      \
            (las_void*)(&stg[row & 127][0]), 16, 0, 0);                       \
      }                                                                       \
    }                                                                         \
    asm volatile("s_waitcnt vmcnt(8)" ::: "memory");                          \
    float sv[32];                                                             \
    const int Lb = 32 * c + 1;                                                \
    const int ra = 16 * c + 31 - t;                                           \
    sv[0] = stg[ra & 127][2 * t + 1];                                         \
    _Pragma("unroll")                                                         \
    for (int k = 1; k <= 15; ++k) {                                           \
      float2 xy = *(const float2*)&stg[(ra + k) & 127][2 * t];                \
      sv[2 * k - 1] = xy.x;                                                   \
      sv[2 * k]     = xy.y;                                                   \
    }                                                                         \
    sv[31] = stg[(ra + 16) & 127][2 * t];                                     \
    _Pragma("unroll")                                                         \
    for (int qq = 0; qq < 32; qq += 2) {                                      \
      {                                                                       \
        float a = dpp_shl1(v0);                                               \
        v1 = sv[qq] * (a + v0 + v1);                                          \
      }                                                                       \
      {                                                                       \
        float bb = dpp_shr1(v1);                                              \
        v0 = sv[qq + 1] * (v1 + bb + v0);                                     \
      }                                                                       \
    }                                                                         \
    (void)Lb;                                                                 \
  }

  for (int cc = 0; cc < 16; ++cc) {
    CHUNK(2 * cc)
    CHUNK(2 * cc + 1)
    // renormalize every 2 chunks via DPP wave-max (lane 63 holds max)
    float mx = fmaxf(v0, v1);
    mx = dpp_max<0x111>(mx);                   // row_shr:1
    mx = dpp_max<0x112>(mx);                   // row_shr:2
    mx = dpp_max<0x114>(mx);                   // row_shr:4
    mx = dpp_max<0x118>(mx);                   // row_shr:8
    mx = dpp_max<0x142>(mx);                   // row_bcast:15
    mx = dpp_max<0x143>(mx);                   // row_bcast:31
    float mxs = __int_as_float(
        __builtin_amdgcn_readlane(__float_as_int(mx), 63));
    int e = (int)((__float_as_uint(mxs) >> 23) & 255u) - 127;
    float scale = __uint_as_float((unsigned)(127 - e) << 23);
    v0 *= scale; v1 *= scale;
    otally += e;
  }
#undef CHUNK

  // R'[512][512] = -(log2(W) + sum e); raw = R' * ln2
  if (t == 32) raw[m] = -(LOG2F(v0) + (float)otally) * LN2;
}

// ---------------------------------------------------------------------------
// Kernel 4: combine + MSE
// ---------------------------------------------------------------------------
__global__ __launch_bounds__(64) void combine_kernel(
    const float* __restrict__ raw, const float* __restrict__ labels,
    float* __restrict__ out) {
  int lane = threadIdx.x;
  float val = 0.0f;
  if (lane < BATCH) {
    float r0 = raw[0 * BATCH + lane];
    float r1 = raw[1 * BATCH + lane];
    float r2 = raw[2 * BATCH + lane];
    float r3 = raw[3 * BATCH + lane];
    float diff = r0 - r1 - 0.5f * r2 + 0.5f * r3;
    float e = diff - labels[lane];
    val = e * e;
  }
#pragma unroll
  for (int off = 32; off; off >>= 1) val += __shfl_xor(val, off);
  if (lane == 0) out[0] = val * (1.0f / BATCH);
}

// ---------------------------------------------------------------------------
extern "C" void kernel_launch(void* const* d_in, const int* in_sizes, int n_in,
                              void* d_out, int out_size, void* d_ws, size_t ws_size,
                              hipStream_t stream) {
  const float* TGT = (const float*)d_in[0];
  const float* OTH = (const float*)d_in[1];
  const float* X   = (const float*)d_in[2];
  const float* labels = (const float*)d_in[3];
  float* out = (float*)d_out;

  char* ws = (char*)d_ws;
  float* Sband = (float*)ws;                                   // 32 MB
  size_t sband_bytes = (size_t)NMAT * SEQ * 128 * 4;
  unsigned short* Y = (unsigned short*)(ws + sband_bytes);     // 24 MB
  size_t y_bytes = (size_t)3 * BATCH * SEQ * 256 * 2;
  float* raw = (float*)(ws + sband_bytes + y_bytes);           // 512 B
  float* zerorow = raw + NMAT;                                 // 512 B zero page

  hipMemsetAsync(zerorow, 0, 512, stream);
  hipLaunchKernelGGL(prep_kernel, dim3((3 * BATCH * SEQ) / 4), dim3(256), 0, stream,
                     TGT, OTH, X, Y);
  hipLaunchKernelGGL(costmm_kernel, dim3(NMAT, 8), dim3(256), 0, stream, Y, Sband);
  hipLaunchKernelGGL(dtw_kernel, dim3(NMAT), dim3(64), 0, stream, Sband, zerorow, raw);
  hipLaunchKernelGGL(combine_kernel, dim3(1), dim3(64), 0, stream, raw, labels, out);
}

// Round 17
// 63.440 us; speedup vs baseline: 1.1173x; 1.1173x over previous
//
#include <hip/hip_runtime.h>
#include <hip/hip_bf16.h>

#define LOG2E 1.4426950408889634f
#define LN2   0.6931471805599453f

#define BATCH 32
#define SEQ   512
#define DIM   128
#define NMAT  128                   // 4 pairs * 32 batches

#define EXP2F(x) __builtin_amdgcn_exp2f(x)
#define LOG2F(x) __builtin_amdgcn_logf(x)

typedef short bf16x8 __attribute__((ext_vector_type(8)));
typedef float f32x4 __attribute__((ext_vector_type(4)));
typedef __attribute__((address_space(1))) const void gas_void;
typedef __attribute__((address_space(3))) void las_void;

// lane i <- lane i-1 (wave_shr:1); lane 0 receives 0 (W-domain: +inf cost)
__device__ __forceinline__ float dpp_shr1(float x) {
  return __int_as_float(__builtin_amdgcn_update_dpp(
      0, __float_as_int(x), 0x138, 0xF, 0xF, false));
}
// lane i <- lane i+1 (wave_shl:1); lane 63 receives 0
__device__ __forceinline__ float dpp_shl1(float x) {
  return __int_as_float(__builtin_amdgcn_update_dpp(
      0, __float_as_int(x), 0x130, 0xF, 0xF, false));
}
template <int CTRL>
__device__ __forceinline__ float dpp_max(float x) {
  int y = __builtin_amdgcn_update_dpp(
      __float_as_int(x), __float_as_int(x), CTRL, 0xF, 0xF, false);
  return fmaxf(x, __int_as_float(y));
}

// ---------------------------------------------------------------------------
// Kernel 1 (prep): normalize rows, split to bf16 hi/lo, interleave.
// ---------------------------------------------------------------------------
__device__ __forceinline__ unsigned short f2bf_rn(float f) {
  unsigned u = __float_as_uint(f);
  u = (u + 0x7FFF + ((u >> 16) & 1)) >> 16;
  return (unsigned short)u;
}
__device__ __forceinline__ float bf2f(unsigned short h) {
  return __uint_as_float(((unsigned)h) << 16);
}

__global__ __launch_bounds__(256) void prep_kernel(
    const float* __restrict__ tgt, const float* __restrict__ oth,
    const float* __restrict__ x, unsigned short* __restrict__ Y) {
  int gid  = blockIdx.x * blockDim.x + threadIdx.x;
  int wave = gid >> 6;
  int lane = threadIdx.x & 63;
  int set = wave / (BATCH * SEQ);
  int row = wave % (BATCH * SEQ);
  const float* src = (set == 0) ? tgt : ((set == 1) ? oth : x);
  const float2* p = (const float2*)(src + (size_t)row * DIM);
  float2 v = p[lane];
  float s = v.x * v.x + v.y * v.y;
#pragma unroll
  for (int off = 32; off; off >>= 1) s += __shfl_xor(s, off);
  float inv = 1.0f / (sqrtf(s) + 1e-8f);
  float y0 = v.x * inv, y1 = v.y * inv;
  unsigned short h0 = f2bf_rn(y0);
  unsigned short l0 = f2bf_rn(y0 - bf2f(h0));
  unsigned short h1 = f2bf_rn(y1);
  unsigned short l1 = f2bf_rn(y1 - bf2f(h1));
  ushort4 st = {h0, l0, h1, l1};
  ((ushort4*)(Y + (size_t)wave * 256))[lane] = st;
}

// ---------------------------------------------------------------------------
// Kernel 2 (costmm): band-stripe bf16 MFMA GEMM -> Sband[i][d+64] = 2^(-D'),
// j-invalid -> 0.  (round-15 config, verified)
// ---------------------------------------------------------------------------
__global__ __launch_bounds__(256) void costmm_kernel(
    const unsigned short* __restrict__ Y, float* __restrict__ Sband) {
  __shared__ unsigned short As[64 * 64];       // 8 KB
  __shared__ unsigned short Bs[192 * 64];      // 24 KB

  const int s = blockIdx.x;                    // stripe 0..7
  const int m = blockIdx.y;
  const int p = m >> 5, b = m & 31;
  const int setA = (p == 1 || p == 3) ? 0 : 1;
  const int setB = (p <= 1) ? 2 : setA;
  const unsigned short* YA = Y + ((size_t)(setA * BATCH + b)) * SEQ * 256;
  const unsigned short* YB = Y + ((size_t)(setB * BATCH + b)) * SEQ * 256;
  const int i0 = s * 64;
  const int j0 = s * 64 - 64;

  const int t = threadIdx.x;
  const int w = t >> 6, l = t & 63;

  f32x4 acc[4][3];
#pragma unroll
  for (int a = 0; a < 4; ++a)
#pragma unroll
    for (int c = 0; c < 3; ++c) acc[a][c] = (f32x4){0.f, 0.f, 0.f, 0.f};

  const int srow_off = l >> 3;
  const int scb      = ((l & 7) * 16) ^ ((srow_off & 7) * 16);

  for (int slab = 0; slab < 4; ++slab) {
    if (slab) __syncthreads();
#pragma unroll
    for (int q2 = 0; q2 < 2; ++q2) {
      int wi = w * 2 + q2;
      int r = wi * 8 + srow_off;
      const unsigned short* gA = YA + (size_t)(i0 + r) * 256 + slab * 64 + (scb >> 1);
      __builtin_amdgcn_global_load_lds((gas_void*)gA, (las_void*)(As + wi * 512), 16, 0, 0);
    }
#pragma unroll
    for (int q6 = 0; q6 < 6; ++q6) {
      int wi = w * 6 + q6;
      int r = wi * 8 + srow_off;               // 0..191
      int j = j0 + r; j = (j < 0) ? 0 : ((j > 511) ? 511 : j);
      const unsigned short* gB = YB + (size_t)j * 256 + slab * 64 + (scb >> 1);
      __builtin_amdgcn_global_load_lds((gas_void*)gB, (las_void*)(Bs + wi * 512), 16, 0, 0);
    }
    asm volatile("s_waitcnt vmcnt(0)" ::: "memory");
    __syncthreads();

#pragma unroll
    for (int ks = 0; ks < 2; ++ks) {
      bf16x8 af[4], bfr[3];
#pragma unroll
      for (int f = 0; f < 4; ++f) {
        int ra = f * 16 + (l & 15);
        int ca = (ks * 64 + (l >> 4) * 16) ^ ((ra & 7) << 4);
        af[f] = *(const bf16x8*)((const char*)As + ra * 128 + ca);
      }
#pragma unroll
      for (int f = 0; f < 3; ++f) {
        int rb = w * 48 + f * 16 + (l & 15);
        int cb = (ks * 64 + (l >> 4) * 16) ^ ((rb & 7) << 4);
        bfr[f] = *(const bf16x8*)((const char*)Bs + rb * 128 + cb);
      }
#pragma unroll
      for (int fm = 0; fm < 4; ++fm)
#pragma unroll
        for (int fn = 0; fn < 3; ++fn)
          acc[fm][fn] = __builtin_amdgcn_mfma_f32_16x16x32_bf16(
              af[fm], bfr[fn], acc[fm][fn], 0, 0, 0);
    }
  }

  float* Sbm = Sband + (size_t)m * (SEQ * 128);
#pragma unroll
  for (int fm = 0; fm < 4; ++fm)
#pragma unroll
    for (int fn = 0; fn < 3; ++fn)
#pragma unroll
      for (int q = 0; q < 4; ++q) {
        int r = fm * 16 + (l >> 4) * 4 + q;    // 0..63  (i = i0+r)
        int c = w * 48 + fn * 16 + (l & 15);   // 0..191 (j = j0+c)
        unsigned crm = (unsigned)(c - r);      // d+64
        if (crm < 128u) {
          int jreal = j0 + c;
          float dp = (1.0f - acc[fm][fn][q]) * LOG2E;
          float sval = ((unsigned)jreal < 512u) ? EXP2F(-dp) : 0.0f;
          Sbm[((size_t)(i0 + r) << 7) + crm] = sval;
        }
      }
}

// ---------------------------------------------------------------------------
// Kernel 3 (dtw): banded soft-DTW, linear domain, fwd+bwd meet-in-middle.
// Wf from L=1..512, Wb from L=1024..513 — two independent chains interleaved
// in one wave (ILP=2), 512 serial steps instead of 1024. Join at cut L=512:
//   total = sum_t [ v0*(v1b + shr(v1b) + v0b) + v1*v1b ]
// (verified algebraically: v0=Wf@512, v1=Wf@511, v1b=Wb@513, v0b=Wb@514).
// ---------------------------------------------------------------------------
__global__ __launch_bounds__(64) void dtw_kernel(
    const float* __restrict__ Sband, const float* __restrict__ zerorow,
    float* __restrict__ raw) {
  __shared__ float stf[128][128];              // fwd ring (slot = row & 127)
  __shared__ float stb[128][128];              // bwd ring
  const int t = threadIdx.x;
  const int m = blockIdx.x;
  const float* Db = Sband + (size_t)m * (SEQ * 128);

  float v0  = (t == 32) ? 1.0f : 0.0f, v1  = 0.0f;   // fwd seed: W[0][0]=1
  float v0b = (t == 32) ? 1.0f : 0.0f, v1b = 0.0f;   // bwd seed (virtual L=1026)
  int otf = 0, otb = 0;

  // zero-fill fwd slots 96..127 (negative rows -32..-1 in chunks 0-1)
  {
    float4 z4 = make_float4(0.f, 0.f, 0.f, 0.f);
#pragma unroll
    for (int q = 0; q < 16; ++q) {
      int row = 96 + q * 2 + (t >> 5);
      *(float4*)&stf[row][(t & 31) * 4] = z4;
    }
  }
  // fwd prologue: rows 0..63 (32 instrs)
#pragma unroll
  for (int q = 0; q < 32; ++q) {
    int row = q * 2;
    __builtin_amdgcn_global_load_lds(
        (gas_void*)(Db + (size_t)row * 128 + t * 4),
        (las_void*)(&stf[row][0]), 16, 0, 0);
  }
  // bwd prologue: rows 464..543 (40 instrs; rows >511 -> zero page)
#pragma unroll
  for (int q = 0; q < 40; ++q) {
    int row = 464 + q * 2;
    int srow = row + (t >> 5);
    const float* src = (srow < 512) ? (Db + (size_t)srow * 128 + (t & 31) * 4)
                                    : (zerorow + (t & 31) * 4);
    __builtin_amdgcn_global_load_lds((gas_void*)src,
        (las_void*)(&stb[row & 127][0]), 16, 0, 0);
  }

#define CHUNKFB(C_)                                                           \
  {                                                                           \
    const int c = (C_);                                                       \
    {  /* fwd stage rows 16c+64..16c+79 (max 319: no redirect) */             \
      int rbase = 16 * c + 64;                                                \
      _Pragma("unroll")                                                       \
      for (int q = 0; q < 8; ++q) {                                           \
        int row = rbase + q * 2;                                              \
        int srow = row + (t >> 5);                                            \
        __builtin_amdgcn_global_load_lds(                                     \
            (gas_void*)(Db + (size_t)srow * 128 + (t & 31) * 4),              \
            (las_void*)(&stf[row & 127][0]), 16, 0, 0);                       \
      }                                                                       \
    }                                                                         \
    {  /* bwd stage rows 448-16c..463-16c (208..463: no redirect) */          \
      int rbase = 448 - 16 * c;                                               \
      _Pragma("unroll")                                                       \
      for (int q = 0; q < 8; ++q) {                                           \
        int row = rbase + q * 2;                                              \
        int srow = row + (t >> 5);                                            \
        __builtin_amdgcn_global_load_lds(                                     \
            (gas_void*)(Db + (size_t)srow * 128 + (t & 31) * 4),              \
            (las_void*)(&stb[row & 127][0]), 16, 0, 0);                       \
      }                                                                       \
    }                                                                         \
    asm volatile("s_waitcnt vmcnt(16)" ::: "memory");                        \
    float svf[32], svb[32];                                                   \
    const int raf = 16 * c + 31 - t;                                          \
    svf[0] = stf[raf & 127][2 * t + 1];                                       \
    _Pragma("unroll")                                                         \
    for (int k = 1; k <= 15; ++k) {                                           \
      float2 xy = *(const float2*)&stf[(raf + k) & 127][2 * t];               \
      svf[2 * k - 1] = xy.x;                                                  \
      svf[2 * k]     = xy.y;                                                  \
    }                                                                         \
    svf[31] = stf[(raf + 16) & 127][2 * t];                                   \
    const int rab = 512 - 16 * c + 31 - t;                                    \
    svb[0] = stb[rab & 127][2 * t];                                           \
    _Pragma("unroll")                                                         \
    for (int k = 1; k <= 15; ++k) {                                           \
      float2 xy = *(const float2*)&stb[(rab - k) & 127][2 * t];               \
      svb[2 * k - 1] = xy.y;                                                  \
      svb[2 * k]     = xy.x;                                                  \
    }                                                                         \
    svb[31] = stb[(rab - 16) & 127][2 * t + 1];                               \
    _Pragma("unroll")                                                         \
    for (int qq = 0; qq < 32; qq += 2) {                                      \
      /* fwd odd L: 3-op path */                                              \
      float af = dpp_shl1(v0);                                                \
      v1 = svf[qq] * ((v0 + v1) + af);                                        \
      /* bwd even L */                                                        \
      float ab = dpp_shr1(v1b);                                               \
      v0b = svb[qq] * ((v1b + v0b) + ab);                                     \
      /* fwd even L */                                                        \
      float bf = dpp_shr1(v1);                                                \
      v0 = svf[qq + 1] * ((v1 + v0) + bf);                                    \
      /* bwd odd L */                                                         \
      float bb = dpp_shl1(v0b);                                               \
      v1b = svb[qq + 1] * ((v0b + v1b) + bb);                                 \
    }                                                                         \
  }

  for (int cc = 0; cc < 8; ++cc) {
    CHUNKFB(2 * cc)
    CHUNKFB(2 * cc + 1)
    // renormalize both chains every 2 chunks (64 steps: no overflow, 3^64<2^127)
    float mf = fmaxf(v0, v1);
    mf = dpp_max<0x111>(mf); mf = dpp_max<0x112>(mf);
    mf = dpp_max<0x114>(mf); mf = dpp_max<0x118>(mf);
    mf = dpp_max<0x142>(mf); mf = dpp_max<0x143>(mf);
    float mfs = __int_as_float(__builtin_amdgcn_readlane(__float_as_int(mf), 63));
    int ef = (int)((__float_as_uint(mfs) >> 23) & 255u) - 127;
    float sf = __uint_as_float((unsigned)(127 - ef) << 23);
    v0 *= sf; v1 *= sf; otf += ef;

    float mb = fmaxf(v0b, v1b);
    mb = dpp_max<0x111>(mb); mb = dpp_max<0x112>(mb);
    mb = dpp_max<0x114>(mb); mb = dpp_max<0x118>(mb);
    mb = dpp_max<0x142>(mb); mb = dpp_max<0x143>(mb);
    float mbs = __int_as_float(__builtin_amdgcn_readlane(__float_as_int(mb), 63));
    int eb = (int)((__float_as_uint(mbs) >> 23) & 255u) - 127;
    float sb = __uint_as_float((unsigned)(127 - eb) << 23);
    v0b *= sb; v1b *= sb; otb += eb;
  }
#undef CHUNKFB

  // join at cut L=512
  float shb = dpp_shr1(v1b);
  float term = v0 * ((v1b + shb) + v0b) + v1 * v1b;
#pragma unroll
  for (int off = 32; off; off >>= 1) term += __shfl_xor(term, off);
  if (t == 32) raw[m] = -(LOG2F(term) + (float)(otf + otb)) * LN2;
}

// ---------------------------------------------------------------------------
// Kernel 4: combine + MSE
// ---------------------------------------------------------------------------
__global__ __launch_bounds__(64) void combine_kernel(
    const float* __restrict__ raw, const float* __restrict__ labels,
    float* __restrict__ out) {
  int lane = threadIdx.x;
  float val = 0.0f;
  if (lane < BATCH) {
    float r0 = raw[0 * BATCH + lane];
    float r1 = raw[1 * BATCH + lane];
    float r2 = raw[2 * BATCH + lane];
    float r3 = raw[3 * BATCH + lane];
    float diff = r0 - r1 - 0.5f * r2 + 0.5f * r3;
    float e = diff - labels[lane];
    val = e * e;
  }
#pragma unroll
  for (int off = 32; off; off >>= 1) val += __shfl_xor(val, off);
  if (lane == 0) out[0] = val * (1.0f / BATCH);
}

// ---------------------------------------------------------------------------
extern "C" void kernel_launch(void* const* d_in, const int* in_sizes, int n_in,
                              void* d_out, int out_size, void* d_ws, size_t ws_size,
                              hipStream_t stream) {
  const float* TGT = (const float*)d_in[0];
  const float* OTH = (const float*)d_in[1];
  const float* X   = (const float*)d_in[2];
  const float* labels = (const float*)d_in[3];
  float* out = (float*)d_out;

  char* ws = (char*)d_ws;
  float* Sband = (float*)ws;                                   // 32 MB
  size_t sband_bytes = (size_t)NMAT * SEQ * 128 * 4;
  unsigned short* Y = (unsigned short*)(ws + sband_bytes);     // 24 MB
  size_t y_bytes = (size_t)3 * BATCH * SEQ * 256 * 2;
  float* raw = (float*)(ws + sband_bytes + y_bytes);           // 512 B
  float* zerorow = raw + NMAT;                                 // 512 B zero page

  hipMemsetAsync(zerorow, 0, 512, stream);
  hipLaunchKernelGGL(prep_kernel, dim3((3 * BATCH * SEQ) / 4), dim3(256), 0, stream,
                     TGT, OTH, X, Y);
  hipLaunchKernelGGL(costmm_kernel, dim3(8, NMAT), dim3(256), 0, stream, Y, Sband);
  hipLaunchKernelGGL(dtw_kernel, dim3(NMAT), dim3(64), 0, stream, Sband, zerorow, raw);
  hipLaunchKernelGGL(combine_kernel, dim3(1), dim3(64), 0, stream, raw, labels, out);
}